// Round 6
// baseline (106.088 us; speedup 1.0000x reference)
//
#include <hip/hip_runtime.h>
#include <hip/hip_bf16.h>

#define NROWS 16384
#define DIM 64
#define BCOLS 512                     // cols per block: B tile = 64 KB LDS, staged ONCE
#define BROWS 1024                    // rows per block
#define NCS (NROWS / BCOLS)           // 32 col-splits
#define NRG (NROWS / BROWS)           // 16 row-groups

static constexpr float TAU = 0.28f;
static constexpr float EPS = 1e-8f;
// exp(x/TAU) = exp2(x * log2e / TAU), with 2^23 folded in so the MFMA
// accumulator directly produces the Schraudolph integer argument:
//   exp2(x) ~= bitcast_f32( (int)(x * 2^23) + EXPB )
// EXPB = (127 - 0.05753)*2^23; per-term +-3% error averages out across the
// 16384-term row sum (R4/R5 measured absmax 0.0).
static constexpr float EXP2_SCALE = (float)(8388608.0 / (0.28 * 0.6931471805599453));
static constexpr int   EXPB = 1064870600;
static constexpr float LN2F = 0.69314718055994530942f;

using short8   = __attribute__((ext_vector_type(8))) short;
using f32x4    = __attribute__((ext_vector_type(4))) float;
using ushort4v = __attribute__((ext_vector_type(4))) unsigned short;

typedef __attribute__((address_space(1))) const unsigned char ga_t;
typedef __attribute__((address_space(3))) unsigned char la_t;

// Kernel 1: per-row L2 normalize; emit A = bf16(EXP2_SCALE * u_norm),
// W = bf16(u_norm + i_norm), p[n] = (u_norm . i_norm)/TAU, zero total[n],
// zero d_out. Each 16-lane group owns one row.
__global__ __launch_bounds__(256) void prep_kernel(
    const float* __restrict__ u, const float* __restrict__ v,
    __hip_bfloat16* __restrict__ a_out, __hip_bfloat16* __restrict__ w_out,
    float* __restrict__ p_out, float* __restrict__ total, float* __restrict__ out)
{
    const int lane = threadIdx.x & 63;
    const int wv   = threadIdx.x >> 6;
    const int l15  = lane & 15;
    const int row  = blockIdx.x * 16 + wv * 4 + (lane >> 4);

    const float4 uu = *(const float4*)(u + (size_t)row * DIM + l15 * 4);
    const float4 vv = *(const float4*)(v + (size_t)row * DIM + l15 * 4);

    float su = uu.x * uu.x + uu.y * uu.y + uu.z * uu.z + uu.w * uu.w;
    float si = vv.x * vv.x + vv.y * vv.y + vv.z * vv.z + vv.w * vv.w;
    float sd = uu.x * vv.x + uu.y * vv.y + uu.z * vv.z + uu.w * vv.w;
#pragma unroll
    for (int m = 1; m < 16; m <<= 1) {
        su += __shfl_xor(su, m, 64);
        si += __shfl_xor(si, m, 64);
        sd += __shfl_xor(sd, m, 64);
    }
    const float inv_u = 1.0f / fmaxf(sqrtf(su), 1e-12f);
    const float inv_i = 1.0f / fmaxf(sqrtf(si), 1e-12f);

    alignas(8) __hip_bfloat16 a4[4], w4[4];
    const float un[4] = {uu.x * inv_u, uu.y * inv_u, uu.z * inv_u, uu.w * inv_u};
    const float in[4] = {vv.x * inv_i, vv.y * inv_i, vv.z * inv_i, vv.w * inv_i};
#pragma unroll
    for (int r = 0; r < 4; r++) {
        a4[r] = __float2bfloat16(EXP2_SCALE * un[r]);
        w4[r] = __float2bfloat16(un[r] + in[r]);
    }
    *(ushort4v*)((unsigned short*)a_out + (size_t)row * DIM + l15 * 4) = *(ushort4v*)a4;
    *(ushort4v*)((unsigned short*)w_out + (size_t)row * DIM + l15 * 4) = *(ushort4v*)w4;

    if (l15 == 0) {
        p_out[row] = sd * inv_u * inv_i * (1.0f / TAU);
        total[row] = 0.0f;
    }
    if (blockIdx.x == 0 && threadIdx.x == 0) out[0] = 0.0f;
}

// Kernel 2: fused GEMM + Schraudolph-exp + row-sum, SOFTWARE-PIPELINED.
// Geometry = R4 skeleton (512 blocks, 2/CU, 8 waves, rs=4, si=2, stage-once,
// XOR swizzle, ONE barrier). Change: double-buffered accumulators + B-frags.
// Per step: issue MFMAs for tile ct, then run the exp/sum VALU of tile ct-1
// — sched_barrier(0) after each MFMA block pins the distance so the
// scheduler cannot re-tighten the mfma->exp chain (VGPR=52 in R0-R5 showed
// it was consuming results immediately, stalling all 4 waves in phase).
#define LOADB(ct, B0, B1) do {                                                 \
    const int jl_ = (ct) * 16 + l15;                                           \
    B0 = *(const short8*)&blds[(size_t)(jl_ * 8 + (quad ^ sw)) * 8];           \
    B1 = *(const short8*)&blds[(size_t)(jl_ * 8 + ((4 + quad) ^ sw)) * 8];     \
} while (0)

#define MFMA4(ACC, B0, B1) do {                                                \
    _Pragma("unroll")                                                          \
    for (int rs_ = 0; rs_ < 4; rs_++) {                                        \
        f32x4 t_ = {0.f, 0.f, 0.f, 0.f};                                       \
        t_ = __builtin_amdgcn_mfma_f32_16x16x32_bf16(af[rs_][0], B0, t_, 0, 0, 0); \
        ACC[rs_] = __builtin_amdgcn_mfma_f32_16x16x32_bf16(af[rs_][1], B1, t_, 0, 0, 0); \
    }                                                                          \
} while (0)

#define EXP4(ACC) do {                                                         \
    _Pragma("unroll")                                                          \
    for (int rs_ = 0; rs_ < 4; rs_++)                                          \
        _Pragma("unroll")                                                      \
        for (int r_ = 0; r_ < 4; r_++)                                         \
            rowsum[rs_][r_] += __int_as_float((int)ACC[rs_][r_] + EXPB);       \
} while (0)

__global__ __launch_bounds__(512, 4) void score_kernel(
    const __hip_bfloat16* __restrict__ A, const __hip_bfloat16* __restrict__ W,
    float* __restrict__ total)
{
    __shared__ alignas(16) ushort blds[BCOLS * DIM];   // exactly 64 KB

    const int tid  = threadIdx.x;
    const int lane = tid & 63;
    const int wv   = tid >> 6;          // 0..7
    const int l15  = lane & 15;
    const int quad = lane >> 4;
    const int sw   = l15 & 7;
    const int cs   = blockIdx.x & (NCS - 1);
    const int rg   = blockIdx.x >> 5;
    const int col0    = cs * BCOLS;
    const int rowbase = rg * BROWS;

    const ushort* Au = (const ushort*)A;
    const ushort* Wu = (const ushort*)W;

    // Stage B: 4096 16-B chunks; physical slot p -> LDS offset p*16,
    // global chunk c = (p&7) ^ (col&7). Coalesced; XOR-swizzled so every
    // ds_read_b128 below is bank-conflict-free.
#pragma unroll
    for (int q = 0; q < 8; q++) {
        const int pp = q * 512 + tid;
        const int j = pp >> 3;
        const int c = (pp & 7) ^ (j & 7);
        const ushort* g = Wu + (size_t)(col0 + j) * DIM + c * 8;
        __builtin_amdgcn_global_load_lds((ga_t*)g, (la_t*)&blds[(size_t)pp * 8], 16, 0, 0);
    }
    __syncthreads();

#pragma unroll 1
    for (int si = 0; si < 2; si++) {
        const int r0 = rowbase + si * 512 + wv * 64;

        // A fragments: rows r0 + rs*16 + l15, k = kk*32 + quad*8 + [0..7]
        short8 af[4][2];
#pragma unroll
        for (int rs = 0; rs < 4; rs++)
#pragma unroll
            for (int kk = 0; kk < 2; kk++)
                af[rs][kk] = *(const short8*)(
                    Au + (size_t)(r0 + rs * 16 + l15) * DIM + kk * 32 + quad * 8);

        f32x4 rowsum[4];
#pragma unroll
        for (int rs = 0; rs < 4; rs++) rowsum[rs] = {0.f, 0.f, 0.f, 0.f};

        short8 b0a, b1a, b0b, b1b;
        f32x4 accA[4], accB[4];

        LOADB(0, b0a, b1a);
        LOADB(1, b0b, b1b);
        MFMA4(accA, b0a, b1a);
        __builtin_amdgcn_sched_barrier(0);

#pragma unroll 1
        for (int ct = 2; ct < BCOLS / 16; ct += 2) {
            LOADB(ct, b0a, b1a);
            MFMA4(accB, b0b, b1b);
            __builtin_amdgcn_sched_barrier(0);
            EXP4(accA);
            LOADB(ct + 1, b0b, b1b);
            MFMA4(accA, b0a, b1a);
            __builtin_amdgcn_sched_barrier(0);
            EXP4(accB);
        }
        MFMA4(accB, b0b, b1b);
        __builtin_amdgcn_sched_barrier(0);
        EXP4(accA);
        EXP4(accB);

        // Sum over the 16 columns held by each l15-group.
#pragma unroll
        for (int m = 1; m < 16; m <<= 1)
#pragma unroll
            for (int rs = 0; rs < 4; rs++)
#pragma unroll
                for (int r = 0; r < 4; r++)
                    rowsum[rs][r] += __shfl_xor(rowsum[rs][r], m, 64);

        if (l15 == 0) {
#pragma unroll
            for (int rs = 0; rs < 4; rs++)
#pragma unroll
                for (int r = 0; r < 4; r++)
                    atomicAdd(&total[r0 + rs * 16 + quad * 4 + r], rowsum[rs][r]);
        }
    }
}

// Kernel 3: out += mean(log(total + EPS) - p), parallel over 64 blocks.
__global__ __launch_bounds__(256) void finalize_kernel(
    const float* __restrict__ total, const float* __restrict__ p,
    float* __restrict__ out)
{
    __shared__ float red[4];
    const int idx = blockIdx.x * 256 + threadIdx.x;
    float s = __log2f(total[idx] + EPS) * LN2F - p[idx];
#pragma unroll
    for (int m = 1; m < 64; m <<= 1) s += __shfl_xor(s, m, 64);
    if ((threadIdx.x & 63) == 0) red[threadIdx.x >> 6] = s;
    __syncthreads();
    if (threadIdx.x == 0)
        atomicAdd(out, (red[0] + red[1] + red[2] + red[3]) * (1.0f / (float)NROWS));
}

extern "C" void kernel_launch(void* const* d_in, const int* in_sizes, int n_in,
                              void* d_out, int out_size, void* d_ws, size_t ws_size,
                              hipStream_t stream) {
    const float* u = (const float*)d_in[0];
    const float* v = (const float*)d_in[1];

    char* ws = (char*)d_ws;
    __hip_bfloat16* a = (__hip_bfloat16*)(ws);                                  // 2 MB
    __hip_bfloat16* w = (__hip_bfloat16*)(ws + (size_t)NROWS * DIM * 2);        // 2 MB
    float* p   = (float*)(ws + (size_t)NROWS * DIM * 4);                        // 64 KB
    float* tot = (float*)(ws + (size_t)NROWS * DIM * 4 + (size_t)NROWS * 4);    // 64 KB

    prep_kernel<<<NROWS / 16, 256, 0, stream>>>(u, v, a, w, p, tot, (float*)d_out);
    score_kernel<<<NRG * NCS, 512, 0, stream>>>(a, w, tot);
    finalize_kernel<<<NROWS / 256, 256, 0, stream>>>(tot, p, (float*)d_out);
}

// Round 7
// 104.332 us; speedup vs baseline: 1.0168x; 1.0168x over previous
//
#include <hip/hip_runtime.h>
#include <hip/hip_bf16.h>

#define NROWS 16384
#define DIM 64
#define BCOLS 512                     // cols per block: B tile = 64 KB LDS, staged ONCE
#define BROWS 1024                    // rows per block
#define NCS (NROWS / BCOLS)           // 32 col-splits
#define NRG (NROWS / BROWS)           // 16 row-groups

static constexpr float TAU = 0.28f;
static constexpr float EPS = 1e-8f;
// exp(x/TAU) = exp2(x * log2e / TAU), with 2^23 folded in so the MFMA
// accumulator directly produces the Schraudolph integer argument:
//   exp2(x) ~= bitcast_f32( (int)(x * 2^23) + EXPB )
// EXPB = (127 - 0.05753)*2^23; per-term +-3% error averages out across the
// 16384-term row sum (R4/R5/R6 measured absmax 0.0).
static constexpr float EXP2_SCALE = (float)(8388608.0 / (0.28 * 0.6931471805599453));
static constexpr int   EXPB = 1064870600;
static constexpr float LN2F = 0.69314718055994530942f;

using short8   = __attribute__((ext_vector_type(8))) short;
using f32x4    = __attribute__((ext_vector_type(4))) float;
using ushort4v = __attribute__((ext_vector_type(4))) unsigned short;

typedef __attribute__((address_space(1))) const unsigned char ga_t;
typedef __attribute__((address_space(3))) unsigned char la_t;

// Kernel 1: per-row L2 normalize; emit A = bf16(EXP2_SCALE * u_norm),
// W = bf16(u_norm + i_norm), p[n] = (u_norm . i_norm)/TAU, zero total[n],
// zero d_out. Each 16-lane group owns one row.
__global__ __launch_bounds__(256) void prep_kernel(
    const float* __restrict__ u, const float* __restrict__ v,
    __hip_bfloat16* __restrict__ a_out, __hip_bfloat16* __restrict__ w_out,
    float* __restrict__ p_out, float* __restrict__ total, float* __restrict__ out)
{
    const int lane = threadIdx.x & 63;
    const int wv   = threadIdx.x >> 6;
    const int l15  = lane & 15;
    const int row  = blockIdx.x * 16 + wv * 4 + (lane >> 4);

    const float4 uu = *(const float4*)(u + (size_t)row * DIM + l15 * 4);
    const float4 vv = *(const float4*)(v + (size_t)row * DIM + l15 * 4);

    float su = uu.x * uu.x + uu.y * uu.y + uu.z * uu.z + uu.w * uu.w;
    float si = vv.x * vv.x + vv.y * vv.y + vv.z * vv.z + vv.w * vv.w;
    float sd = uu.x * vv.x + uu.y * vv.y + uu.z * vv.z + uu.w * vv.w;
#pragma unroll
    for (int m = 1; m < 16; m <<= 1) {
        su += __shfl_xor(su, m, 64);
        si += __shfl_xor(si, m, 64);
        sd += __shfl_xor(sd, m, 64);
    }
    const float inv_u = 1.0f / fmaxf(sqrtf(su), 1e-12f);
    const float inv_i = 1.0f / fmaxf(sqrtf(si), 1e-12f);

    alignas(8) __hip_bfloat16 a4[4], w4[4];
    const float un[4] = {uu.x * inv_u, uu.y * inv_u, uu.z * inv_u, uu.w * inv_u};
    const float in[4] = {vv.x * inv_i, vv.y * inv_i, vv.z * inv_i, vv.w * inv_i};
#pragma unroll
    for (int r = 0; r < 4; r++) {
        a4[r] = __float2bfloat16(EXP2_SCALE * un[r]);
        w4[r] = __float2bfloat16(un[r] + in[r]);
    }
    *(ushort4v*)((unsigned short*)a_out + (size_t)row * DIM + l15 * 4) = *(ushort4v*)a4;
    *(ushort4v*)((unsigned short*)w_out + (size_t)row * DIM + l15 * 4) = *(ushort4v*)w4;

    if (l15 == 0) {
        p_out[row] = sd * inv_u * inv_i * (1.0f / TAU);
        total[row] = 0.0f;
    }
    if (blockIdx.x == 0 && threadIdx.x == 0) out[0] = 0.0f;
}

// Kernel 2: fused GEMM + Schraudolph-exp + row-sum, CONVOY-BROKEN.
// Geometry = R4 proven skeleton (512 blocks, 2/CU, 8 waves, rs=4, si=2,
// stage-once, XOR swizzle, ONE barrier). Two changes, one theory (cross-wave
// phase desync — R0-R6 counters show pipes serializing: MFMA 13.4us + VALU
// 9us + LDS 10us summing to ~40us of a 47us kernel):
//  (1) per-wave ct rotation: wave wv sweeps B tiles starting at (wv*4)&31,
//      so co-resident waves are never in the same burst phase (sum is
//      commutative -> bit-identical result ordering per row... (fp add
//      reassociation only, same as any col order; threshold has huge slack)).
//  (2) sched_group_barrier per ct: {2 DS_READ, 8 x (1 MFMA + 6 VALU)} —
//      burst length drops 128cyc -> ~16cyc so mis-phased waves interleave.
__global__ __launch_bounds__(512, 4) void score_kernel(
    const __hip_bfloat16* __restrict__ A, const __hip_bfloat16* __restrict__ W,
    float* __restrict__ total)
{
    __shared__ alignas(16) ushort blds[BCOLS * DIM];   // exactly 64 KB

    const int tid  = threadIdx.x;
    const int lane = tid & 63;
    const int wv   = tid >> 6;          // 0..7
    const int l15  = lane & 15;
    const int quad = lane >> 4;
    const int sw   = l15 & 7;
    const int cs   = blockIdx.x & (NCS - 1);
    const int rg   = blockIdx.x >> 5;
    const int col0    = cs * BCOLS;
    const int rowbase = rg * BROWS;

    const ushort* Au = (const ushort*)A;
    const ushort* Wu = (const ushort*)W;

    // Stage B: 4096 16-B chunks; physical slot p -> LDS offset p*16,
    // global chunk c = (p&7) ^ (col&7). Coalesced; XOR-swizzled so every
    // ds_read_b128 below is bank-conflict-free.
#pragma unroll
    for (int q = 0; q < 8; q++) {
        const int pp = q * 512 + tid;
        const int j = pp >> 3;
        const int c = (pp & 7) ^ (j & 7);
        const ushort* g = Wu + (size_t)(col0 + j) * DIM + c * 8;
        __builtin_amdgcn_global_load_lds((ga_t*)g, (la_t*)&blds[(size_t)pp * 8], 16, 0, 0);
    }
    __syncthreads();

#pragma unroll 1
    for (int si = 0; si < 2; si++) {
        const int r0 = rowbase + si * 512 + wv * 64;

        // A fragments: rows r0 + rs*16 + l15, k = kk*32 + quad*8 + [0..7]
        short8 af[4][2];
#pragma unroll
        for (int rs = 0; rs < 4; rs++)
#pragma unroll
            for (int kk = 0; kk < 2; kk++)
                af[rs][kk] = *(const short8*)(
                    Au + (size_t)(r0 + rs * 16 + l15) * DIM + kk * 32 + quad * 8);

        f32x4 rowsum[4];
#pragma unroll
        for (int rs = 0; rs < 4; rs++) rowsum[rs] = {0.f, 0.f, 0.f, 0.f};

#pragma unroll 4
        for (int ct = 0; ct < BCOLS / 16; ct++) {
            const int ctr = (ct + wv * 4) & 31;          // per-wave phase shift
            const int jl = ctr * 16 + l15;
            const short8 b0 = *(const short8*)&blds[(size_t)(jl * 8 + (quad ^ sw)) * 8];
            const short8 b1 = *(const short8*)&blds[(size_t)(jl * 8 + ((4 + quad) ^ sw)) * 8];
#pragma unroll
            for (int rs = 0; rs < 4; rs++) {
                f32x4 acc = {0.f, 0.f, 0.f, 0.f};
                acc = __builtin_amdgcn_mfma_f32_16x16x32_bf16(af[rs][0], b0, acc, 0, 0, 0);
                acc = __builtin_amdgcn_mfma_f32_16x16x32_bf16(af[rs][1], b1, acc, 0, 0, 0);
#pragma unroll
                for (int r = 0; r < 4; r++)
                    rowsum[rs][r] += __int_as_float((int)acc[r] + EXPB);
            }
            // Shape the per-iteration schedule: ds_reads first, then a fine
            // 1-MFMA : 6-VALU interleave (48 VALU = 16 cvt + 16 iadd + 16 fadd).
            __builtin_amdgcn_sched_group_barrier(0x100, 2, 0);   // DS_READ x2
#pragma unroll
            for (int g = 0; g < 8; g++) {
                __builtin_amdgcn_sched_group_barrier(0x008, 1, 0); // MFMA x1
                __builtin_amdgcn_sched_group_barrier(0x002, 6, 0); // VALU x6
            }
        }

        // Sum over the 16 columns held by each l15-group.
#pragma unroll
        for (int m = 1; m < 16; m <<= 1)
#pragma unroll
            for (int rs = 0; rs < 4; rs++)
#pragma unroll
                for (int r = 0; r < 4; r++)
                    rowsum[rs][r] += __shfl_xor(rowsum[rs][r], m, 64);

        if (l15 == 0) {
#pragma unroll
            for (int rs = 0; rs < 4; rs++)
#pragma unroll
                for (int r = 0; r < 4; r++)
                    atomicAdd(&total[r0 + rs * 16 + quad * 4 + r], rowsum[rs][r]);
        }
    }
}

// Kernel 3: out += mean(log(total + EPS) - p), parallel over 64 blocks.
__global__ __launch_bounds__(256) void finalize_kernel(
    const float* __restrict__ total, const float* __restrict__ p,
    float* __restrict__ out)
{
    __shared__ float red[4];
    const int idx = blockIdx.x * 256 + threadIdx.x;
    float s = __log2f(total[idx] + EPS) * LN2F - p[idx];
#pragma unroll
    for (int m = 1; m < 64; m <<= 1) s += __shfl_xor(s, m, 64);
    if ((threadIdx.x & 63) == 0) red[threadIdx.x >> 6] = s;
    __syncthreads();
    if (threadIdx.x == 0)
        atomicAdd(out, (red[0] + red[1] + red[2] + red[3]) * (1.0f / (float)NROWS));
}

extern "C" void kernel_launch(void* const* d_in, const int* in_sizes, int n_in,
                              void* d_out, int out_size, void* d_ws, size_t ws_size,
                              hipStream_t stream) {
    const float* u = (const float*)d_in[0];
    const float* v = (const float*)d_in[1];

    char* ws = (char*)d_ws;
    __hip_bfloat16* a = (__hip_bfloat16*)(ws);                                  // 2 MB
    __hip_bfloat16* w = (__hip_bfloat16*)(ws + (size_t)NROWS * DIM * 2);        // 2 MB
    float* p   = (float*)(ws + (size_t)NROWS * DIM * 4);                        // 64 KB
    float* tot = (float*)(ws + (size_t)NROWS * DIM * 4 + (size_t)NROWS * 4);    // 64 KB

    prep_kernel<<<NROWS / 16, 256, 0, stream>>>(u, v, a, w, p, tot, (float*)d_out);
    score_kernel<<<NRG * NCS, 512, 0, stream>>>(a, w, tot);
    finalize_kernel<<<NROWS / 256, 256, 0, stream>>>(tot, p, (float*)d_out);
}